// Round 2
// baseline (296.728 us; speedup 1.0000x reference)
//
#include <hip/hip_runtime.h>
#include <hip/hip_bf16.h>
#include <stdint.h>

#define DEV __device__ __forceinline__

typedef short     s16x8  __attribute__((ext_vector_type(8)));
typedef __bf16    bf16v8 __attribute__((ext_vector_type(8)));
typedef float     f32x4  __attribute__((ext_vector_type(4)));
typedef float     f32x16 __attribute__((ext_vector_type(16)));

// ---------- helpers ----------
DEV unsigned short f2bf(float x) {
    uint32_t u = __float_as_uint(x);
    uint32_t r = (u + 0x7FFFu + ((u >> 16) & 1u)) >> 16;
    return (unsigned short)r;
}

DEV void gload_lds16(const void* g, void* l) {
    __builtin_amdgcn_global_load_lds((const __attribute__((address_space(1))) void*)g,
                                     (__attribute__((address_space(3))) void*)l,
                                     16, 0, 0);
}

DEV f32x4 mfma16(s16x8 a, s16x8 b, f32x4 c) {
    return __builtin_amdgcn_mfma_f32_16x16x32_bf16(
        __builtin_bit_cast(bf16v8, a), __builtin_bit_cast(bf16v8, b), c, 0, 0, 0);
}
DEV f32x16 mfma32(s16x8 a, s16x8 b, f32x16 c) {
    return __builtin_amdgcn_mfma_f32_32x32x16_bf16(
        __builtin_bit_cast(bf16v8, a), __builtin_bit_cast(bf16v8, b), c, 0, 0, 0);
}

DEV uint32_t cvtpk_bf16(float lo, float hi) {
    uint32_t r;
    asm volatile("v_cvt_pk_bf16_f32 %0, %1, %2" : "=v"(r) : "v"(lo), "v"(hi));
    return r;
}

// ---------- elementwise f32 -> bf16 (8 elems / thread) ----------
__global__ void f32_to_bf16_k(const float* __restrict__ in, short* __restrict__ out, int n8) {
    int i = blockIdx.x * blockDim.x + threadIdx.x;
    if (i >= n8) return;
    const float4 a = *(const float4*)(in + (size_t)i * 8);
    const float4 b = *(const float4*)(in + (size_t)i * 8 + 4);
    uint4 w;
    w.x = (uint32_t)f2bf(a.x) | ((uint32_t)f2bf(a.y) << 16);
    w.y = (uint32_t)f2bf(a.z) | ((uint32_t)f2bf(a.w) << 16);
    w.z = (uint32_t)f2bf(b.x) | ((uint32_t)f2bf(b.y) << 16);
    w.w = (uint32_t)f2bf(b.z) | ((uint32_t)f2bf(b.w) << 16);
    *(uint4*)(out + (size_t)i * 8) = w;
}

// ---------- tiled transpose f32 (R x C) -> bf16 (C x R) ----------
__global__ __launch_bounds__(256) void transpose_f32_bf16_k(
    const float* __restrict__ in, size_t in_batch, int ld_in,
    short* __restrict__ out, size_t out_batch, int ld_out) {
    __shared__ float tile[64][65];
    const float* ip = in + (size_t)blockIdx.z * in_batch;
    short* op = out + (size_t)blockIdx.z * out_batch;
    const int c0 = blockIdx.x * 64, r0 = blockIdx.y * 64;
    const int t = threadIdx.x;
    const int cc4 = (t & 15) * 4;
    const int rr  = t >> 4;
#pragma unroll
    for (int p = 0; p < 4; ++p) {
        int r = rr + p * 16;
        float4 v = *(const float4*)(ip + (size_t)(r0 + r) * ld_in + c0 + cc4);
        tile[r][cc4 + 0] = v.x; tile[r][cc4 + 1] = v.y;
        tile[r][cc4 + 2] = v.z; tile[r][cc4 + 3] = v.w;
    }
    __syncthreads();
#pragma unroll
    for (int p = 0; p < 4; ++p) {
        int oc  = (t >> 4) + p * 16;
        int rr4 = (t & 15) * 4;
        ushort4 w;
        w.x = f2bf(tile[rr4 + 0][oc]);
        w.y = f2bf(tile[rr4 + 1][oc]);
        w.z = f2bf(tile[rr4 + 2][oc]);
        w.w = f2bf(tile[rr4 + 3][oc]);
        *(ushort4*)(op + (size_t)(c0 + oc) * ld_out + r0 + rr4) = w;
    }
}

// ---------- bias concat ----------
__global__ void concat_bias_k(const float* __restrict__ bq, const float* __restrict__ bk,
                              const float* __restrict__ bv, float* __restrict__ o) {
    int i = blockIdx.x * 256 + threadIdx.x;
    if (i < 2048)       o[i] = bq[i];
    else if (i < 2560)  o[i] = bk[i - 2048];
    else if (i < 3072)  o[i] = bv[i - 2560];
}

// ---------- GEMM: C[M,N] = A[M,K](bf16) * Bt[N,K](bf16)^T + bias, f32 out ----------
// 128x128 tile, BK=64, 4 waves (2x2), double-buffered global_load_lds staging.
// T1: XCD-bijective block swizzle (grids are %8==0).
__global__ __launch_bounds__(256, 2) void gemm_bt_k(
    const short* __restrict__ A, const short* __restrict__ Bt,
    const float* __restrict__ bias, float* __restrict__ C,
    int M, int N, int K) {
    __shared__ short As[2][128 * 64];
    __shared__ short Bs[2][128 * 64];
    const int tid = threadIdx.x;
    const int nwg = gridDim.x * gridDim.y;
    const int flat = blockIdx.y * gridDim.x + blockIdx.x;
    const int cpx = nwg >> 3;
    const int swz = (flat & 7) * cpx + (flat >> 3);
    const int m0 = (swz / gridDim.x) * 128, n0 = (swz % gridDim.x) * 128;
    const int lane = tid & 63;
    const int wid = tid >> 6;
    const int wm = wid >> 1, wn = wid & 1;
    const int lr = lane & 15, lg = lane >> 4;

    const short* ag[4]; const short* bg[4]; int lb[4];
#pragma unroll
    for (int i = 0; i < 4; ++i) {
        int oo = (i * 256 + tid) * 8;
        int row = oo >> 6, col = oo & 63;
        ag[i] = A + (size_t)(m0 + row) * K + col;
        bg[i] = Bt + (size_t)(n0 + row) * K + col;
        lb[i] = (i * 256 + (tid & ~63)) * 8;
    }

    f32x4 acc[4][4];
#pragma unroll
    for (int m = 0; m < 4; ++m)
#pragma unroll
        for (int n = 0; n < 4; ++n)
#pragma unroll
            for (int r = 0; r < 4; ++r) acc[m][n][r] = 0.f;

    const int nk = K >> 6;
    // prologue
#pragma unroll
    for (int i = 0; i < 4; ++i) gload_lds16(ag[i], &As[0][lb[i]]);
#pragma unroll
    for (int i = 0; i < 4; ++i) gload_lds16(bg[i], &Bs[0][lb[i]]);
    asm volatile("s_waitcnt vmcnt(0)");
    __syncthreads();

    int cur = 0;
    for (int kt = 0; kt < nk; ++kt) {
        if (kt + 1 < nk) {
            const int ko = (kt + 1) * 64;
#pragma unroll
            for (int i = 0; i < 4; ++i) gload_lds16(ag[i] + ko, &As[cur ^ 1][lb[i]]);
#pragma unroll
            for (int i = 0; i < 4; ++i) gload_lds16(bg[i] + ko, &Bs[cur ^ 1][lb[i]]);
        }
#pragma unroll
        for (int kk = 0; kk < 2; ++kk) {
            s16x8 af[4], bfr[4];
#pragma unroll
            for (int m = 0; m < 4; ++m)
                af[m] = *(const s16x8*)&As[cur][(wm * 64 + m * 16 + lr) * 64 + kk * 32 + lg * 8];
#pragma unroll
            for (int n = 0; n < 4; ++n)
                bfr[n] = *(const s16x8*)&Bs[cur][(wn * 64 + n * 16 + lr) * 64 + kk * 32 + lg * 8];
#pragma unroll
            for (int m = 0; m < 4; ++m)
#pragma unroll
                for (int n = 0; n < 4; ++n)
                    acc[m][n] = mfma16(af[m], bfr[n], acc[m][n]);
        }
        asm volatile("s_waitcnt vmcnt(0)");
        __syncthreads();
        cur ^= 1;
    }

#pragma unroll
    for (int n = 0; n < 4; ++n) {
        const int col = n0 + wn * 64 + n * 16 + lr;
        const float bb = bias[col];
#pragma unroll
        for (int m = 0; m < 4; ++m) {
            const int rbase = m0 + wm * 64 + m * 16 + lg * 4;
#pragma unroll
            for (int r = 0; r < 4; ++r)
                C[(size_t)(rbase + r) * N + col] = acc[m][n][r] + bb;
        }
    }
}

// ---------- rmsnorm + rope + head layout for Q,K ----------
__global__ __launch_bounds__(256) void qkv_post_k(
    const float* __restrict__ Y, const float* __restrict__ qn_w,
    const float* __restrict__ kn_w, const int* __restrict__ start_pos,
    short* __restrict__ Qb, short* __restrict__ Kb) {
    const int m = blockIdx.x;
    const int b = m >> 11, s = m & 2047;
    const float* y = Y + (size_t)m * 3072;
    const int tid = threadIdx.x;

    const float4 q1 = *(const float4*)(y + tid * 8);
    const float4 q2 = *(const float4*)(y + tid * 8 + 4);
    const float2 kv = *(const float2*)(y + 2048 + tid * 2);
    float ssq = q1.x * q1.x + q1.y * q1.y + q1.z * q1.z + q1.w * q1.w
              + q2.x * q2.x + q2.y * q2.y + q2.z * q2.z + q2.w * q2.w;
    float ssk = kv.x * kv.x + kv.y * kv.y;
#pragma unroll
    for (int off = 1; off < 64; off <<= 1) {
        ssq += __shfl_xor(ssq, off);
        ssk += __shfl_xor(ssk, off);
    }
    __shared__ float red[8];
    if ((tid & 63) == 0) { red[tid >> 6] = ssq; red[4 + (tid >> 6)] = ssk; }
    __syncthreads();
    const float tq = red[0] + red[1] + red[2] + red[3];
    const float tk = red[4] + red[5] + red[6] + red[7];
    const float rq = rsqrtf(tq * (1.f / 2048.f) + 1.1920929e-07f);
    const float rk = rsqrtf(tk * (1.f / 512.f) + 1.1920929e-07f);
    const int pos = start_pos[0] + s;

    float qn[8];
    qn[0] = q1.x; qn[1] = q1.y; qn[2] = q1.z; qn[3] = q1.w;
    qn[4] = q2.x; qn[5] = q2.y; qn[6] = q2.z; qn[7] = q2.w;
#pragma unroll
    for (int j = 0; j < 8; ++j) qn[j] *= rq * qn_w[tid * 8 + j];
    const int hq = tid >> 4;
    const int din = (tid * 8) & 127;
    unsigned short ob[8];
#pragma unroll
    for (int j = 0; j < 4; ++j) {
        int tt = (din >> 1) + j;
        float inv = __builtin_exp2f(-0.20762050f * (float)tt);
        float ang = (float)pos * inv;
        float sn, cn;
        __sincosf(ang, &sn, &cn);
        float x1 = qn[2 * j], x2 = qn[2 * j + 1];
        ob[2 * j]     = f2bf(x1 * cn - x2 * sn);
        ob[2 * j + 1] = f2bf(x1 * sn + x2 * cn);
    }
    short* qdst = Qb + (((size_t)(b * 16 + hq) * 2048 + s) * 128 + din);
    uint4 w;
    w.x = (uint32_t)ob[0] | ((uint32_t)ob[1] << 16);
    w.y = (uint32_t)ob[2] | ((uint32_t)ob[3] << 16);
    w.z = (uint32_t)ob[4] | ((uint32_t)ob[5] << 16);
    w.w = (uint32_t)ob[6] | ((uint32_t)ob[7] << 16);
    *(uint4*)qdst = w;

    const int colk = tid * 2;
    const int hk = colk >> 7, dk = colk & 127;
    float k1 = kv.x * rk * kn_w[colk], k2 = kv.y * rk * kn_w[colk + 1];
    {
        int tt = dk >> 1;
        float inv = __builtin_exp2f(-0.20762050f * (float)tt);
        float ang = (float)pos * inv;
        float sn, cn;
        __sincosf(ang, &sn, &cn);
        float r1 = k1 * cn - k2 * sn, r2 = k1 * sn + k2 * cn;
        short* kdst = Kb + (((size_t)(b * 4 + hk) * 2048 + s) * 128 + dk);
        *(uint32_t*)kdst = (uint32_t)f2bf(r1) | ((uint32_t)f2bf(r2) << 16);
    }
}

// ---------- flash attention v2: group-fused, 32-kv subtile pipeline ----------
// grid: (64 qtiles of 32 rows, reversed; 8 = b*4+hk). 4 waves = 4 heads of the
// GQA group, all covering the SAME 32 q-rows -> shared K/V staging, uniform
// causal range, wave-uniform mask fast-path.
__global__ __launch_bounds__(256, 2) void attn_fwd_k(
    const short* __restrict__ Qb, const short* __restrict__ Kb,
    const short* __restrict__ Vtb, const float* __restrict__ gate_logits,
    short* __restrict__ attnb) {
    const int S = 2048;
    __shared__ short Ks[2][64 * 128];
    __shared__ short Vs[2][128 * 64];
    const int tid = threadIdx.x, lane = tid & 63;
    const int wid = tid >> 6;                 // head within group
    const int qt = 63 - (int)blockIdx.x;      // reversed for load balance
    const int bhk = blockIdx.y;               // b*4+hk
    const int b = bhk >> 2, hk = bhk & 3;
    const int h = hk * 4 + wid;
    const int q0 = qt * 32;
    const int ql = lane & 31, hi = lane >> 5;
    const int qg = q0 + ql;

    s16x8 qf[8];
    {
        const short* qrow = Qb + (((size_t)(b * 16 + h) * S + qg) * 128 + hi * 8);
#pragma unroll
        for (int kc = 0; kc < 8; ++kc) qf[kc] = *(const s16x8*)(qrow + kc * 16);
    }
    f32x16 ov[4];
#pragma unroll
    for (int dc = 0; dc < 4; ++dc)
#pragma unroll
        for (int r = 0; r < 16; ++r) ov[dc][r] = 0.f;
    float mrun = -3.0e38f, lrun = 0.f;
    const float cs = 0.12751745f;     // (1/sqrt(128)) * log2(e)
    const float THR = 90.509668f;     // 8*sqrt(128)

    const short* kg[4]; const short* vg[4]; int lb[4];
#pragma unroll
    for (int i = 0; i < 4; ++i) {
        int oo = (i * 256 + tid) * 8;
        lb[i] = (i * 256 + (tid & ~63)) * 8;
        {
            int row = oo >> 7, col = oo & 127, ch = col >> 3;
            kg[i] = Kb + ((size_t)bhk * S + row) * 128 + ((ch ^ (row & 7)) << 3);
        }
        {
            int row = oo >> 6, col = oo & 63, ch = col >> 3;
            vg[i] = Vtb + ((size_t)bhk * 128 + row) * S + ((ch ^ (row & 7)) << 3);
        }
    }
    const int ntiles = ((q0 + 31) >> 6) + 1;
#pragma unroll
    for (int i = 0; i < 4; ++i) gload_lds16(kg[i], &Ks[0][lb[i]]);
#pragma unroll
    for (int i = 0; i < 4; ++i) gload_lds16(vg[i], &Vs[0][lb[i]]);
    asm volatile("s_waitcnt vmcnt(0)");
    __syncthreads();

    int cur = 0;
    for (int jt = 0; jt < ntiles; ++jt) {
        const int j0 = jt * 64;
        if (jt + 1 < ntiles) {
            const int jn = j0 + 64;
#pragma unroll
            for (int i = 0; i < 4; ++i) gload_lds16(kg[i] + (size_t)jn * 128, &Ks[cur ^ 1][lb[i]]);
#pragma unroll
            for (int i = 0; i < 4; ++i) gload_lds16(vg[i] + jn, &Vs[cur ^ 1][lb[i]]);
        }
#pragma unroll
        for (int t = 0; t < 2; ++t) {
            const int jb = j0 + t * 32;
            if (jb > q0 + 31) continue;             // subtile fully masked
            const bool fsub = (jb + 31 <= q0);      // subtile fully unmasked (wave-uniform)
            // ---- QK^T (swapped): 8 MFMA, sacc row m = kv-local, col n = q = ql
            f32x16 sacc;
#pragma unroll
            for (int r = 0; r < 16; ++r) sacc[r] = 0.f;
            const int krl = t * 32 + ql;
#pragma unroll
            for (int kc = 0; kc < 8; ++kc) {
                int ch = kc * 2 + hi;
                s16x8 kf = *(const s16x8*)&Ks[cur][krl * 128 + ((ch ^ (krl & 7)) << 3)];
                sacc = mfma32(kf, qf[kc], sacc);
            }
            float p[16];
            if (fsub) {
#pragma unroll
                for (int r = 0; r < 16; ++r) p[r] = sacc[r];
            } else {
#pragma unroll
                for (int r = 0; r < 16; ++r) {
                    int kvg = jb + ((r & 3) + 8 * (r >> 2) + 4 * hi);
                    p[r] = (kvg <= qg) ? sacc[r] : -3.0e38f;
                }
            }
            // ---- max (tree) + cross-half
            float m0a = fmaxf(p[0], p[1]),  m1a = fmaxf(p[2], p[3]);
            float m2a = fmaxf(p[4], p[5]),  m3a = fmaxf(p[6], p[7]);
            float m4a = fmaxf(p[8], p[9]),  m5a = fmaxf(p[10], p[11]);
            float m6a = fmaxf(p[12], p[13]), m7a = fmaxf(p[14], p[15]);
            float mb0 = fmaxf(m0a, m1a), mb1 = fmaxf(m2a, m3a);
            float mb2 = fmaxf(m4a, m5a), mb3 = fmaxf(m6a, m7a);
            float pmax = fmaxf(fmaxf(mb0, mb1), fmaxf(mb2, mb3));
            pmax = fmaxf(pmax, __shfl_xor(pmax, 32));
            if (__any(pmax - mrun > THR)) {
                float mnew = fmaxf(mrun, pmax);
                float alpha = __builtin_exp2f((mrun - mnew) * cs);
                lrun *= alpha;
#pragma unroll
                for (int r = 0; r < 16; ++r) {
                    int cr = (r & 3) + 8 * (r >> 2) + 4 * hi;
                    float ar = __uint_as_float(
                        (uint32_t)__builtin_amdgcn_ds_bpermute(cr << 2, (int)__float_as_uint(alpha)));
                    ov[0][r] *= ar; ov[1][r] *= ar; ov[2][r] *= ar; ov[3][r] *= ar;
                }
                mrun = mnew;
            }
#pragma unroll
            for (int r = 0; r < 16; ++r) p[r] = __builtin_exp2f((p[r] - mrun) * cs);
            // ---- sum (tree) + cross-half
            float s0a = p[0] + p[1],  s1a = p[2] + p[3];
            float s2a = p[4] + p[5],  s3a = p[6] + p[7];
            float s4a = p[8] + p[9],  s5a = p[10] + p[11];
            float s6a = p[12] + p[13], s7a = p[14] + p[15];
            float ps = ((s0a + s1a) + (s2a + s3a)) + ((s4a + s5a) + (s6a + s7a));
            ps += __shfl_xor(ps, 32);
            lrun += ps;
            // ---- pack to bf16 A-fragments (2 k-slices of 16)
            uint32_t w0 = cvtpk_bf16(p[0], p[1]),   w1 = cvtpk_bf16(p[2], p[3]);
            uint32_t w2 = cvtpk_bf16(p[4], p[5]),   w3 = cvtpk_bf16(p[6], p[7]);
            uint32_t w4 = cvtpk_bf16(p[8], p[9]),   w5 = cvtpk_bf16(p[10], p[11]);
            uint32_t w6 = cvtpk_bf16(p[12], p[13]), w7 = cvtpk_bf16(p[14], p[15]);
            uint32_t w0s = (uint32_t)__shfl_xor((int)w0, 32);
            uint32_t w1s = (uint32_t)__shfl_xor((int)w1, 32);
            uint32_t w2s = (uint32_t)__shfl_xor((int)w2, 32);
            uint32_t w3s = (uint32_t)__shfl_xor((int)w3, 32);
            uint32_t w4s = (uint32_t)__shfl_xor((int)w4, 32);
            uint32_t w5s = (uint32_t)__shfl_xor((int)w5, 32);
            uint32_t w6s = (uint32_t)__shfl_xor((int)w6, 32);
            uint32_t w7s = (uint32_t)__shfl_xor((int)w7, 32);
            union { uint32_t u[4]; s16x8 v; } pa0, pa1;
            pa0.u[0] = hi ? w2s : w0;  pa0.u[1] = hi ? w3s : w1;
            pa0.u[2] = hi ? w2  : w0s; pa0.u[3] = hi ? w3  : w1s;
            pa1.u[0] = hi ? w6s : w4;  pa1.u[1] = hi ? w7s : w5;
            pa1.u[2] = hi ? w6  : w4s; pa1.u[3] = hi ? w7  : w5s;
            // ---- PV: 8 MFMA
#pragma unroll
            for (int dc = 0; dc < 4; ++dc) {
                int d = dc * 32 + ql;
                int c0i = t * 4 + hi;
                s16x8 vf0 = *(const s16x8*)&Vs[cur][d * 64 + ((c0i ^ (d & 7)) << 3)];
                ov[dc] = mfma32(pa0.v, vf0, ov[dc]);
                int c1i = t * 4 + 2 + hi;
                s16x8 vf1 = *(const s16x8*)&Vs[cur][d * 64 + ((c1i ^ (d & 7)) << 3)];
                ov[dc] = mfma32(pa1.v, vf1, ov[dc]);
            }
        }
        asm volatile("s_waitcnt vmcnt(0)");
        __syncthreads();
        cur ^= 1;
    }
    // epilogue: gate * O / l
    const float gl = gate_logits[h];
    const float gate = 1.f / (1.f + __expf(-gl));
    const float linv = gate / lrun;
#pragma unroll
    for (int r = 0; r < 16; ++r) {
        int cr = (r & 3) + 8 * (r >> 2) + 4 * hi;
        float sc = __uint_as_float(
            (uint32_t)__builtin_amdgcn_ds_bpermute(cr << 2, (int)__float_as_uint(linv)));
        int qrow = q0 + cr;
        short* orow = attnb + ((size_t)(b * S) + qrow) * 2048 + h * 128 + ql;
#pragma unroll
        for (int dc = 0; dc < 4; ++dc)
            orow[dc * 32] = (short)f2bf(ov[dc][r] * sc);
    }
}

// ---------- launch ----------
extern "C" void kernel_launch(void* const* d_in, const int* in_sizes, int n_in,
                              void* d_out, int out_size, void* d_ws, size_t ws_size,
                              hipStream_t stream) {
    const float* x  = (const float*)d_in[0];
    const float* Wq = (const float*)d_in[1];
    const float* bq = (const float*)d_in[2];
    const float* Wk = (const float*)d_in[3];
    const float* bk = (const float*)d_in[4];
    const float* Wv = (const float*)d_in[5];
    const float* bv = (const float*)d_in[6];
    const float* Wo = (const float*)d_in[7];
    const float* bo = (const float*)d_in[8];
    const float* qn = (const float*)d_in[9];
    const float* kn = (const float*)d_in[10];
    const float* gl = (const float*)d_in[11];
    const int* sp   = (const int*)d_in[13];
    float* out = (float*)d_out;

    char* ws = (char*)d_ws;
    const size_t NEED = 96481280;
    if (ws_size < NEED) return;
    short* xb    = (short*)(ws + 0);            // 16 MiB, reused as Qb
    short* wqkvT = (short*)(ws + 16777216);     // 12 MiB
    short* woT   = (short*)(ws + 29360128);     // 8 MiB
    float* bqkv  = (float*)(ws + 37748736);     // 12 KiB
    float* Y     = (float*)(ws + 37761024);     // 48 MiB, head reused as attnb
    short* Kb    = (short*)(ws + 88092672);     // 4 MiB
    short* Vtb   = (short*)(ws + 92286976);     // 4 MiB
    short* Qb    = xb;
    short* attnb = (short*)Y;

    f32_to_bf16_k<<<4096, 256, 0, stream>>>(x, xb, 1048576);
    transpose_f32_bf16_k<<<dim3(32, 32, 1), 256, 0, stream>>>(Wq, 0, 2048, wqkvT, 0, 2048);
    transpose_f32_bf16_k<<<dim3(8, 32, 1), 256, 0, stream>>>(Wk, 0, 512, wqkvT + (size_t)2048 * 2048, 0, 2048);
    transpose_f32_bf16_k<<<dim3(8, 32, 1), 256, 0, stream>>>(Wv, 0, 512, wqkvT + (size_t)2560 * 2048, 0, 2048);
    transpose_f32_bf16_k<<<dim3(32, 32, 1), 256, 0, stream>>>(Wo, 0, 2048, woT, 0, 2048);
    concat_bias_k<<<12, 256, 0, stream>>>(bq, bk, bv, bqkv);
    gemm_bt_k<<<dim3(24, 32), 256, 0, stream>>>(xb, wqkvT, bqkv, Y, 4096, 3072, 2048);
    qkv_post_k<<<4096, 256, 0, stream>>>(Y, qn, kn, sp, Qb, Kb);
    transpose_f32_bf16_k<<<dim3(8, 32, 2), 256, 0, stream>>>(
        Y + 2560, (size_t)2048 * 3072, 3072, Vtb, (size_t)512 * 2048, 2048);
    attn_fwd_k<<<dim3(64, 8), 256, 0, stream>>>(Qb, Kb, Vtb, gl, attnb);
    gemm_bt_k<<<dim3(16, 32), 256, 0, stream>>>(attnb, woT, bo, out, 4096, 2048, 2048);
}

// Round 5
// 280.199 us; speedup vs baseline: 1.0590x; 1.0590x over previous
//
#include <hip/hip_runtime.h>
#include <hip/hip_bf16.h>
#include <stdint.h>

#define DEV __device__ __forceinline__

typedef short     s16x8  __attribute__((ext_vector_type(8)));
typedef __bf16    bf16v8 __attribute__((ext_vector_type(8)));
typedef float     f32x4  __attribute__((ext_vector_type(4)));
typedef float     f32x16 __attribute__((ext_vector_type(16)));

// ---------- helpers ----------
DEV unsigned short f2bf(float x) {
    uint32_t u = __float_as_uint(x);
    uint32_t r = (u + 0x7FFFu + ((u >> 16) & 1u)) >> 16;
    return (unsigned short)r;
}

DEV void gload_lds16(const void* g, void* l) {
    __builtin_amdgcn_global_load_lds((const __attribute__((address_space(1))) void*)g,
                                     (__attribute__((address_space(3))) void*)l,
                                     16, 0, 0);
}

DEV f32x4 mfma16(s16x8 a, s16x8 b, f32x4 c) {
    return __builtin_amdgcn_mfma_f32_16x16x32_bf16(
        __builtin_bit_cast(bf16v8, a), __builtin_bit_cast(bf16v8, b), c, 0, 0, 0);
}
DEV f32x16 mfma32(s16x8 a, s16x8 b, f32x16 c) {
    return __builtin_amdgcn_mfma_f32_32x32x16_bf16(
        __builtin_bit_cast(bf16v8, a), __builtin_bit_cast(bf16v8, b), c, 0, 0, 0);
}

DEV uint32_t cvtpk_bf16(float lo, float hi) {
    uint32_t r;
    asm volatile("v_cvt_pk_bf16_f32 %0, %1, %2" : "=v"(r) : "v"(lo), "v"(hi));
    return r;
}

// ---------- elementwise f32 -> bf16 (8 elems / thread) ----------
__global__ void f32_to_bf16_k(const float* __restrict__ in, short* __restrict__ out, int n8) {
    int i = blockIdx.x * blockDim.x + threadIdx.x;
    if (i >= n8) return;
    const float4 a = *(const float4*)(in + (size_t)i * 8);
    const float4 b = *(const float4*)(in + (size_t)i * 8 + 4);
    uint4 w;
    w.x = (uint32_t)f2bf(a.x) | ((uint32_t)f2bf(a.y) << 16);
    w.y = (uint32_t)f2bf(a.z) | ((uint32_t)f2bf(a.w) << 16);
    w.z = (uint32_t)f2bf(b.x) | ((uint32_t)f2bf(b.y) << 16);
    w.w = (uint32_t)f2bf(b.z) | ((uint32_t)f2bf(b.w) << 16);
    *(uint4*)(out + (size_t)i * 8) = w;
}

// ---------- tiled transpose f32 (R x C) -> bf16 (C x R) ----------
__global__ __launch_bounds__(256) void transpose_f32_bf16_k(
    const float* __restrict__ in, size_t in_batch, int ld_in,
    short* __restrict__ out, size_t out_batch, int ld_out) {
    __shared__ float tile[64][65];
    const float* ip = in + (size_t)blockIdx.z * in_batch;
    short* op = out + (size_t)blockIdx.z * out_batch;
    const int c0 = blockIdx.x * 64, r0 = blockIdx.y * 64;
    const int t = threadIdx.x;
    const int cc4 = (t & 15) * 4;
    const int rr  = t >> 4;
#pragma unroll
    for (int p = 0; p < 4; ++p) {
        int r = rr + p * 16;
        float4 v = *(const float4*)(ip + (size_t)(r0 + r) * ld_in + c0 + cc4);
        tile[r][cc4 + 0] = v.x; tile[r][cc4 + 1] = v.y;
        tile[r][cc4 + 2] = v.z; tile[r][cc4 + 3] = v.w;
    }
    __syncthreads();
#pragma unroll
    for (int p = 0; p < 4; ++p) {
        int oc  = (t >> 4) + p * 16;
        int rr4 = (t & 15) * 4;
        ushort4 w;
        w.x = f2bf(tile[rr4 + 0][oc]);
        w.y = f2bf(tile[rr4 + 1][oc]);
        w.z = f2bf(tile[rr4 + 2][oc]);
        w.w = f2bf(tile[rr4 + 3][oc]);
        *(ushort4*)(op + (size_t)(c0 + oc) * ld_out + r0 + rr4) = w;
    }
}

// ---------- bias concat ----------
__global__ void concat_bias_k(const float* __restrict__ bq, const float* __restrict__ bk,
                              const float* __restrict__ bv, float* __restrict__ o) {
    int i = blockIdx.x * 256 + threadIdx.x;
    if (i < 2048)       o[i] = bq[i];
    else if (i < 2560)  o[i] = bk[i - 2048];
    else if (i < 3072)  o[i] = bv[i - 2560];
}

// ---------- GEMM: C[M,N] = A[M,K](bf16) * Bt[N,K](bf16)^T + bias, f32 out ----------
__global__ __launch_bounds__(256, 2) void gemm_bt_k(
    const short* __restrict__ A, const short* __restrict__ Bt,
    const float* __restrict__ bias, float* __restrict__ C,
    int M, int N, int K) {
    __shared__ short As[2][128 * 64];
    __shared__ short Bs[2][128 * 64];
    const int tid = threadIdx.x;
    const int nwg = gridDim.x * gridDim.y;
    const int flat = blockIdx.y * gridDim.x + blockIdx.x;
    const int cpx = nwg >> 3;
    const int swz = (flat & 7) * cpx + (flat >> 3);
    const int m0 = (swz / gridDim.x) * 128, n0 = (swz % gridDim.x) * 128;
    const int lane = tid & 63;
    const int wid = tid >> 6;
    const int wm = wid >> 1, wn = wid & 1;
    const int lr = lane & 15, lg = lane >> 4;

    const short* ag[4]; const short* bg[4]; int lb[4];
#pragma unroll
    for (int i = 0; i < 4; ++i) {
        int oo = (i * 256 + tid) * 8;
        int row = oo >> 6, col = oo & 63;
        ag[i] = A + (size_t)(m0 + row) * K + col;
        bg[i] = Bt + (size_t)(n0 + row) * K + col;
        lb[i] = (i * 256 + (tid & ~63)) * 8;
    }

    f32x4 acc[4][4];
#pragma unroll
    for (int m = 0; m < 4; ++m)
#pragma unroll
        for (int n = 0; n < 4; ++n)
#pragma unroll
            for (int r = 0; r < 4; ++r) acc[m][n][r] = 0.f;

    const int nk = K >> 6;
#pragma unroll
    for (int i = 0; i < 4; ++i) gload_lds16(ag[i], &As[0][lb[i]]);
#pragma unroll
    for (int i = 0; i < 4; ++i) gload_lds16(bg[i], &Bs[0][lb[i]]);
    asm volatile("s_waitcnt vmcnt(0)");
    __syncthreads();

    int cur = 0;
    for (int kt = 0; kt < nk; ++kt) {
        if (kt + 1 < nk) {
            const int ko = (kt + 1) * 64;
#pragma unroll
            for (int i = 0; i < 4; ++i) gload_lds16(ag[i] + ko, &As[cur ^ 1][lb[i]]);
#pragma unroll
            for (int i = 0; i < 4; ++i) gload_lds16(bg[i] + ko, &Bs[cur ^ 1][lb[i]]);
        }
#pragma unroll
        for (int kk = 0; kk < 2; ++kk) {
            s16x8 af[4], bfr[4];
#pragma unroll
            for (int m = 0; m < 4; ++m)
                af[m] = *(const s16x8*)&As[cur][(wm * 64 + m * 16 + lr) * 64 + kk * 32 + lg * 8];
#pragma unroll
            for (int n = 0; n < 4; ++n)
                bfr[n] = *(const s16x8*)&Bs[cur][(wn * 64 + n * 16 + lr) * 64 + kk * 32 + lg * 8];
#pragma unroll
            for (int m = 0; m < 4; ++m)
#pragma unroll
                for (int n = 0; n < 4; ++n)
                    acc[m][n] = mfma16(af[m], bfr[n], acc[m][n]);
        }
        asm volatile("s_waitcnt vmcnt(0)");
        __syncthreads();
        cur ^= 1;
    }

#pragma unroll
    for (int n = 0; n < 4; ++n) {
        const int col = n0 + wn * 64 + n * 16 + lr;
        const float bb = bias[col];
#pragma unroll
        for (int m = 0; m < 4; ++m) {
            const int rbase = m0 + wm * 64 + m * 16 + lg * 4;
#pragma unroll
            for (int r = 0; r < 4; ++r)
                C[(size_t)(rbase + r) * N + col] = acc[m][n][r] + bb;
        }
    }
}

// ---------- rmsnorm + rope + head layout for Q,K ----------
__global__ __launch_bounds__(256) void qkv_post_k(
    const float* __restrict__ Y, const float* __restrict__ qn_w,
    const float* __restrict__ kn_w, const int* __restrict__ start_pos,
    short* __restrict__ Qb, short* __restrict__ Kb) {
    const int m = blockIdx.x;
    const int b = m >> 11, s = m & 2047;
    const float* y = Y + (size_t)m * 3072;
    const int tid = threadIdx.x;

    const float4 q1 = *(const float4*)(y + tid * 8);
    const float4 q2 = *(const float4*)(y + tid * 8 + 4);
    const float2 kv = *(const float2*)(y + 2048 + tid * 2);
    float ssq = q1.x * q1.x + q1.y * q1.y + q1.z * q1.z + q1.w * q1.w
              + q2.x * q2.x + q2.y * q2.y + q2.z * q2.z + q2.w * q2.w;
    float ssk = kv.x * kv.x + kv.y * kv.y;
#pragma unroll
    for (int off = 1; off < 64; off <<= 1) {
        ssq += __shfl_xor(ssq, off);
        ssk += __shfl_xor(ssk, off);
    }
    __shared__ float red[8];
    if ((tid & 63) == 0) { red[tid >> 6] = ssq; red[4 + (tid >> 6)] = ssk; }
    __syncthreads();
    const float tq = red[0] + red[1] + red[2] + red[3];
    const float tk = red[4] + red[5] + red[6] + red[7];
    const float rq = rsqrtf(tq * (1.f / 2048.f) + 1.1920929e-07f);
    const float rk = rsqrtf(tk * (1.f / 512.f) + 1.1920929e-07f);
    const int pos = start_pos[0] + s;

    float qn[8];
    qn[0] = q1.x; qn[1] = q1.y; qn[2] = q1.z; qn[3] = q1.w;
    qn[4] = q2.x; qn[5] = q2.y; qn[6] = q2.z; qn[7] = q2.w;
#pragma unroll
    for (int j = 0; j < 8; ++j) qn[j] *= rq * qn_w[tid * 8 + j];
    const int hq = tid >> 4;
    const int din = (tid * 8) & 127;
    unsigned short ob[8];
#pragma unroll
    for (int j = 0; j < 4; ++j) {
        int tt = (din >> 1) + j;
        float inv = __builtin_exp2f(-0.20762050f * (float)tt);
        float ang = (float)pos * inv;
        float sn, cn;
        __sincosf(ang, &sn, &cn);
        float x1 = qn[2 * j], x2 = qn[2 * j + 1];
        ob[2 * j]     = f2bf(x1 * cn - x2 * sn);
        ob[2 * j + 1] = f2bf(x1 * sn + x2 * cn);
    }
    short* qdst = Qb + (((size_t)(b * 16 + hq) * 2048 + s) * 128 + din);
    uint4 w;
    w.x = (uint32_t)ob[0] | ((uint32_t)ob[1] << 16);
    w.y = (uint32_t)ob[2] | ((uint32_t)ob[3] << 16);
    w.z = (uint32_t)ob[4] | ((uint32_t)ob[5] << 16);
    w.w = (uint32_t)ob[6] | ((uint32_t)ob[7] << 16);
    *(uint4*)qdst = w;

    const int colk = tid * 2;
    const int hk = colk >> 7, dk = colk & 127;
    float k1 = kv.x * rk * kn_w[colk], k2 = kv.y * rk * kn_w[colk + 1];
    {
        int tt = dk >> 1;
        float inv = __builtin_exp2f(-0.20762050f * (float)tt);
        float ang = (float)pos * inv;
        float sn, cn;
        __sincosf(ang, &sn, &cn);
        float r1 = k1 * cn - k2 * sn, r2 = k1 * sn + k2 * cn;
        short* kdst = Kb + (((size_t)(b * 4 + hk) * 2048 + s) * 128 + dk);
        *(uint32_t*)kdst = (uint32_t)f2bf(r1) | ((uint32_t)f2bf(r2) << 16);
    }
}

// ---------- flash attention v4: LPT dispatch + setprio, r2-proven datapath ----
// grid: (8 = b*4+hk fast, 64 qtiles with qt = 63 - y) -> longest blocks first
// (LPT schedule). 4 waves = 4 heads of the GQA group on the same 32 q-rows;
// shared K/V staging. Cross-half ops via __shfl_xor (ds_permute) — the
// permlane32_swap inline-asm path corrupted data (rounds 3/4): cross-lane
// read hazards inside an asm blob get no compiler-inserted wait states.
__global__ __launch_bounds__(256, 2) void attn_fwd_k(
    const short* __restrict__ Qb, const short* __restrict__ Kb,
    const short* __restrict__ Vtb, const float* __restrict__ gate_logits,
    short* __restrict__ attnb) {
    const int S = 2048;
    __shared__ short Ks[2][64 * 128];
    __shared__ short Vs[2][128 * 64];
    const int tid = threadIdx.x, lane = tid & 63;
    const int wid = tid >> 6;                 // head within group
    const int qt = 63 - (int)blockIdx.y;      // LPT: longest first
    const int bhk = blockIdx.x;               // b*4+hk
    const int b = bhk >> 2, hk = bhk & 3;
    const int h = hk * 4 + wid;
    const int q0 = qt * 32;
    const int ql = lane & 31, hi = lane >> 5;
    const int qg = q0 + ql;

    s16x8 qf[8];
    {
        const short* qrow = Qb + (((size_t)(b * 16 + h) * S + qg) * 128 + hi * 8);
#pragma unroll
        for (int kc = 0; kc < 8; ++kc) qf[kc] = *(const s16x8*)(qrow + kc * 16);
    }
    f32x16 ov[4];
#pragma unroll
    for (int dc = 0; dc < 4; ++dc)
#pragma unroll
        for (int r = 0; r < 16; ++r) ov[dc][r] = 0.f;
    float mrun = -3.0e38f, lrun = 0.f;
    const float cs = 0.12751745f;     // (1/sqrt(128)) * log2(e)
    const float THR = 90.509668f;     // 8*sqrt(128)

    const short* kg[4]; const short* vg[4]; int lb[4];
#pragma unroll
    for (int i = 0; i < 4; ++i) {
        int oo = (i * 256 + tid) * 8;
        lb[i] = (i * 256 + (tid & ~63)) * 8;
        {
            int row = oo >> 7, col = oo & 127, ch = col >> 3;
            kg[i] = Kb + ((size_t)bhk * S + row) * 128 + ((ch ^ (row & 7)) << 3);
        }
        {
            int row = oo >> 6, col = oo & 63, ch = col >> 3;
            vg[i] = Vtb + ((size_t)bhk * 128 + row) * S + ((ch ^ (row & 7)) << 3);
        }
    }
    const int ntiles = ((q0 + 31) >> 6) + 1;
#pragma unroll
    for (int i = 0; i < 4; ++i) gload_lds16(kg[i], &Ks[0][lb[i]]);
#pragma unroll
    for (int i = 0; i < 4; ++i) gload_lds16(vg[i], &Vs[0][lb[i]]);
    asm volatile("s_waitcnt vmcnt(0)");
    __syncthreads();

    int cur = 0;
    for (int jt = 0; jt < ntiles; ++jt) {
        const int j0 = jt * 64;
        if (jt + 1 < ntiles) {
            const int jn = j0 + 64;
#pragma unroll
            for (int i = 0; i < 4; ++i) gload_lds16(kg[i] + (size_t)jn * 128, &Ks[cur ^ 1][lb[i]]);
#pragma unroll
            for (int i = 0; i < 4; ++i) gload_lds16(vg[i] + jn, &Vs[cur ^ 1][lb[i]]);
        }
#pragma unroll
        for (int t = 0; t < 2; ++t) {
            const int jb = j0 + t * 32;
            if (jb > q0 + 31) continue;             // subtile fully masked
            const bool fsub = (jb + 31 <= q0);      // fully unmasked (wave-uniform)
            // ---- QK^T (swapped): 8 MFMA
            f32x16 sacc;
#pragma unroll
            for (int r = 0; r < 16; ++r) sacc[r] = 0.f;
            const int krl = t * 32 + ql;
            __builtin_amdgcn_s_setprio(1);
#pragma unroll
            for (int kc = 0; kc < 8; ++kc) {
                int ch = kc * 2 + hi;
                s16x8 kf = *(const s16x8*)&Ks[cur][krl * 128 + ((ch ^ (krl & 7)) << 3)];
                sacc = mfma32(kf, qf[kc], sacc);
            }
            __builtin_amdgcn_s_setprio(0);
            float p[16];
            if (fsub) {
#pragma unroll
                for (int r = 0; r < 16; ++r) p[r] = sacc[r];
            } else {
#pragma unroll
                for (int r = 0; r < 16; ++r) {
                    int kvg = jb + ((r & 3) + 8 * (r >> 2) + 4 * hi);
                    p[r] = (kvg <= qg) ? sacc[r] : -3.0e38f;
                }
            }
            // ---- max (tree) + cross-half
            float m0a = fmaxf(p[0], p[1]),  m1a = fmaxf(p[2], p[3]);
            float m2a = fmaxf(p[4], p[5]),  m3a = fmaxf(p[6], p[7]);
            float m4a = fmaxf(p[8], p[9]),  m5a = fmaxf(p[10], p[11]);
            float m6a = fmaxf(p[12], p[13]), m7a = fmaxf(p[14], p[15]);
            float mb0 = fmaxf(m0a, m1a), mb1 = fmaxf(m2a, m3a);
            float mb2 = fmaxf(m4a, m5a), mb3 = fmaxf(m6a, m7a);
            float pmax = fmaxf(fmaxf(mb0, mb1), fmaxf(mb2, mb3));
            pmax = fmaxf(pmax, __shfl_xor(pmax, 32));
            if (__any(pmax - mrun > THR)) {
                float mnew = fmaxf(mrun, pmax);
                float alpha = __builtin_exp2f((mrun - mnew) * cs);
                lrun *= alpha;
#pragma unroll
                for (int r = 0; r < 16; ++r) {
                    int cr = (r & 3) + 8 * (r >> 2) + 4 * hi;
                    float ar = __uint_as_float(
                        (uint32_t)__builtin_amdgcn_ds_bpermute(cr << 2, (int)__float_as_uint(alpha)));
                    ov[0][r] *= ar; ov[1][r] *= ar; ov[2][r] *= ar; ov[3][r] *= ar;
                }
                mrun = mnew;
            }
#pragma unroll
            for (int r = 0; r < 16; ++r) p[r] = __builtin_exp2f((p[r] - mrun) * cs);
            // ---- sum (tree) + cross-half
            float s0a = p[0] + p[1],  s1a = p[2] + p[3];
            float s2a = p[4] + p[5],  s3a = p[6] + p[7];
            float s4a = p[8] + p[9],  s5a = p[10] + p[11];
            float s6a = p[12] + p[13], s7a = p[14] + p[15];
            float ps = ((s0a + s1a) + (s2a + s3a)) + ((s4a + s5a) + (s6a + s7a));
            ps += __shfl_xor(ps, 32);
            lrun += ps;
            // ---- pack to bf16 A-fragments (r2-proven shfl path)
            uint32_t w0 = cvtpk_bf16(p[0], p[1]),   w1 = cvtpk_bf16(p[2], p[3]);
            uint32_t w2 = cvtpk_bf16(p[4], p[5]),   w3 = cvtpk_bf16(p[6], p[7]);
            uint32_t w4 = cvtpk_bf16(p[8], p[9]),   w5 = cvtpk_bf16(p[10], p[11]);
            uint32_t w6 = cvtpk_bf16(p[12], p[13]), w7 = cvtpk_bf16(p[14], p[15]);
            uint32_t w0s = (uint32_t)__shfl_xor((int)w0, 32);
            uint32_t w1s = (uint32_t)__shfl_xor((int)w1, 32);
            uint32_t w2s = (uint32_t)__shfl_xor((int)w2, 32);
            uint32_t w3s = (uint32_t)__shfl_xor((int)w3, 32);
            uint32_t w4s = (uint32_t)__shfl_xor((int)w4, 32);
            uint32_t w5s = (uint32_t)__shfl_xor((int)w5, 32);
            uint32_t w6s = (uint32_t)__shfl_xor((int)w6, 32);
            uint32_t w7s = (uint32_t)__shfl_xor((int)w7, 32);
            union { uint32_t u[4]; s16x8 v; } pa0, pa1;
            pa0.u[0] = hi ? w2s : w0;  pa0.u[1] = hi ? w3s : w1;
            pa0.u[2] = hi ? w2  : w0s; pa0.u[3] = hi ? w3  : w1s;
            pa1.u[0] = hi ? w6s : w4;  pa1.u[1] = hi ? w7s : w5;
            pa1.u[2] = hi ? w6  : w4s; pa1.u[3] = hi ? w7  : w5s;
            // ---- PV: 8 MFMA
            __builtin_amdgcn_s_setprio(1);
#pragma unroll
            for (int dc = 0; dc < 4; ++dc) {
                int d = dc * 32 + ql;
                int c0i = t * 4 + hi;
                s16x8 vf0 = *(const s16x8*)&Vs[cur][d * 64 + ((c0i ^ (d & 7)) << 3)];
                ov[dc] = mfma32(pa0.v, vf0, ov[dc]);
                int c1i = t * 4 + 2 + hi;
                s16x8 vf1 = *(const s16x8*)&Vs[cur][d * 64 + ((c1i ^ (d & 7)) << 3)];
                ov[dc] = mfma32(pa1.v, vf1, ov[dc]);
            }
            __builtin_amdgcn_s_setprio(0);
        }
        asm volatile("s_waitcnt vmcnt(0)");
        __syncthreads();
        cur ^= 1;
    }
    // epilogue: gate * O / l
    const float gl = gate_logits[h];
    const float gate = 1.f / (1.f + __expf(-gl));
    const float linv = gate / lrun;
#pragma unroll
    for (int r = 0; r < 16; ++r) {
        int cr = (r & 3) + 8 * (r >> 2) + 4 * hi;
        float sc = __uint_as_float(
            (uint32_t)__builtin_amdgcn_ds_bpermute(cr << 2, (int)__float_as_uint(linv)));
        int qrow = q0 + cr;
        short* orow = attnb + ((size_t)(b * S) + qrow) * 2048 + h * 128 + ql;
#pragma unroll
        for (int dc = 0; dc < 4; ++dc)
            orow[dc * 32] = (short)f2bf(ov[dc][r] * sc);
    }
}

// ---------- launch ----------
extern "C" void kernel_launch(void* const* d_in, const int* in_sizes, int n_in,
                              void* d_out, int out_size, void* d_ws, size_t ws_size,
                              hipStream_t stream) {
    const float* x  = (const float*)d_in[0];
    const float* Wq = (const float*)d_in[1];
    const float* bq = (const float*)d_in[2];
    const float* Wk = (const float*)d_in[3];
    const float* bk = (const float*)d_in[4];
    const float* Wv = (const float*)d_in[5];
    const float* bv = (const float*)d_in[6];
    const float* Wo = (const float*)d_in[7];
    const float* bo = (const float*)d_in[8];
    const float* qn = (const float*)d_in[9];
    const float* kn = (const float*)d_in[10];
    const float* gl = (const float*)d_in[11];
    const int* sp   = (const int*)d_in[13];
    float* out = (float*)d_out;

    char* ws = (char*)d_ws;
    const size_t NEED = 96481280;
    if (ws_size < NEED) return;
    short* xb    = (short*)(ws + 0);            // 16 MiB, reused as Qb
    short* wqkvT = (short*)(ws + 16777216);     // 12 MiB
    short* woT   = (short*)(ws + 29360128);     // 8 MiB
    float* bqkv  = (float*)(ws + 37748736);     // 12 KiB
    float* Y     = (float*)(ws + 37761024);     // 48 MiB, head reused as attnb
    short* Kb    = (short*)(ws + 88092672);     // 4 MiB
    short* Vtb   = (short*)(ws + 92286976);     // 4 MiB
    short* Qb    = xb;
    short* attnb = (short*)Y;

    f32_to_bf16_k<<<4096, 256, 0, stream>>>(x, xb, 1048576);
    transpose_f32_bf16_k<<<dim3(32, 32, 1), 256, 0, stream>>>(Wq, 0, 2048, wqkvT, 0, 2048);
    transpose_f32_bf16_k<<<dim3(8, 32, 1), 256, 0, stream>>>(Wk, 0, 512, wqkvT + (size_t)2048 * 2048, 0, 2048);
    transpose_f32_bf16_k<<<dim3(8, 32, 1), 256, 0, stream>>>(Wv, 0, 512, wqkvT + (size_t)2560 * 2048, 0, 2048);
    transpose_f32_bf16_k<<<dim3(32, 32, 1), 256, 0, stream>>>(Wo, 0, 2048, woT, 0, 2048);
    concat_bias_k<<<12, 256, 0, stream>>>(bq, bk, bv, bqkv);
    gemm_bt_k<<<dim3(24, 32), 256, 0, stream>>>(xb, wqkvT, bqkv, Y, 4096, 3072, 2048);
    qkv_post_k<<<4096, 256, 0, stream>>>(Y, qn, kn, sp, Qb, Kb);
    transpose_f32_bf16_k<<<dim3(8, 32, 2), 256, 0, stream>>>(
        Y + 2560, (size_t)2048 * 3072, 3072, Vtb, (size_t)512 * 2048, 2048);
    attn_fwd_k<<<dim3(8, 64), 256, 0, stream>>>(Qb, Kb, Vtb, gl, attnb);
    gemm_bt_k<<<dim3(16, 32), 256, 0, stream>>>(attnb, woT, bo, out, 4096, 2048, 2048);
}